// Round 5
// baseline (338.592 us; speedup 1.0000x reference)
//
#include <hip/hip_runtime.h>
#include <hip/hip_bf16.h>

#define N_NODES 50000
#define N_EDGES 800000
#define IN_DIM 128
#define HIDDEN 128
#define OUT_DIM 40

#define SCAN_BS 1024
#define SCAN_BLOCKS ((N_NODES + SCAN_BS - 1) / SCAN_BS)   // 49

#define N_BUCKETS 8
#define BUCKET_NODES ((N_NODES + N_BUCKETS - 1) / N_BUCKETS)   // 6250
#define PART_BLOCKS 256                                        // 32 chunks x 8 buckets
#define CHUNK_EDGES (N_EDGES / (PART_BLOCKS / N_BUCKETS))      // 25000

struct __align__(8) Edge { int s; float w; };

// ---- 1) bucket-partitioned histogram of dst -------------------------------
// bucket q = blockIdx&7 -> (heuristically) XCD q; all atomics on cnt slice q
// stay in one XCD's L2 -> no cross-XCD line ping-pong.
__global__ __launch_bounds__(256) void hist_part(const int* __restrict__ dst,
                                                 int* __restrict__ cnt)
{
    int q = blockIdx.x & (N_BUCKETS - 1);
    int chunk = blockIdx.x >> 3;
    int base = chunk * CHUNK_EDGES;
    int lo = q * BUCKET_NODES;
    int hi = lo + BUCKET_NODES;
    for (int i = base + threadIdx.x; i < base + CHUNK_EDGES; i += 256) {
        int d = dst[i];
        if (d >= lo && d < hi) atomicAdd(&cnt[d], 1);
    }
}

// ---- 2a) per-block partial sums -------------------------------------------
__global__ __launch_bounds__(SCAN_BS) void scan_partial(const int* __restrict__ cnt,
                                                        int* __restrict__ block_sums)
{
    __shared__ int red[SCAN_BS / 64];
    int i = blockIdx.x * SCAN_BS + threadIdx.x;
    int v = (i < N_NODES) ? cnt[i] : 0;
    for (int off = 32; off > 0; off >>= 1) v += __shfl_down(v, off, 64);
    int wave = threadIdx.x >> 6, lane = threadIdx.x & 63;
    if (lane == 0) red[wave] = v;
    __syncthreads();
    if (threadIdx.x == 0) {
        int s = 0;
        #pragma unroll
        for (int wv = 0; wv < SCAN_BS / 64; ++wv) s += red[wv];
        block_sums[blockIdx.x] = s;
    }
}

// ---- 2b) scan the 49 block sums (one wave) --------------------------------
__global__ __launch_bounds__(64) void scan_sums(int* __restrict__ block_sums,
                                                int* __restrict__ row_ptr)
{
    int t = threadIdx.x;
    int v = (t < SCAN_BLOCKS) ? block_sums[t] : 0;
    int incl = v;
    for (int off = 1; off < 64; off <<= 1) {
        int u = __shfl_up(incl, off, 64);
        if (t >= off) incl += u;
    }
    if (t < SCAN_BLOCKS) block_sums[t] = incl - v;
    if (t == 0) row_ptr[N_NODES] = N_EDGES;
}

// ---- 2c) block-local exclusive scan + offset ------------------------------
__global__ __launch_bounds__(SCAN_BS) void scan_final(const int* __restrict__ cnt,
                                                      const int* __restrict__ block_sums,
                                                      int* __restrict__ row_ptr,
                                                      int* __restrict__ cursor)
{
    __shared__ int tmp[SCAN_BS];
    int t = threadIdx.x;
    int i = blockIdx.x * SCAN_BS + t;
    int v = (i < N_NODES) ? cnt[i] : 0;
    tmp[t] = v;
    __syncthreads();
    for (int off = 1; off < SCAN_BS; off <<= 1) {
        int u = (t >= off) ? tmp[t - off] : 0;
        __syncthreads();
        tmp[t] += u;
        __syncthreads();
    }
    if (i < N_NODES) {
        int excl = tmp[t] - v + block_sums[blockIdx.x];
        row_ptr[i] = excl;
        cursor[i]  = excl;
    }
}

// ---- 3) bucket-partitioned scatter into dst-sorted order ------------------
// Each bucket's 800 KB output region is written only by blocks of that
// bucket (one XCD) -> L2 merges the 8B writes into full lines.
__global__ __launch_bounds__(256) void scatter_part(const int* __restrict__ src,
                                                    const int* __restrict__ dst,
                                                    const float* __restrict__ w,
                                                    int* __restrict__ cursor,
                                                    Edge* __restrict__ edges)
{
    int q = blockIdx.x & (N_BUCKETS - 1);
    int chunk = blockIdx.x >> 3;
    int base = chunk * CHUNK_EDGES;
    int lo = q * BUCKET_NODES;
    int hi = lo + BUCKET_NODES;
    for (int i = base + threadIdx.x; i < base + CHUNK_EDGES; i += 256) {
        int d = dst[i];
        int s = src[i];
        float wv = w[i];
        if (d >= lo && d < hi) {
            int pos = atomicAdd(&cursor[d], 1);
            Edge ed; ed.s = s; ed.w = wv;
            edges[pos] = ed;
        }
    }
}

// ---- gemm1: y = x @ W1 (fp32 in, bf16 out), 16 rows/block -----------------
#define G1_ROWS 16
__global__ __launch_bounds__(128) void gemm1_kernel(const float* __restrict__ x,
                                                    const float* __restrict__ W1,
                                                    __hip_bfloat16* __restrict__ y)
{
    __shared__ float xs[G1_ROWS][IN_DIM];
    int row0 = blockIdx.x * G1_ROWS;
    int col = threadIdx.x;
    #pragma unroll
    for (int r = 0; r < G1_ROWS; ++r)
        xs[r][col] = x[(long long)(row0 + r) * IN_DIM + col];
    __syncthreads();
    float acc[G1_ROWS];
    #pragma unroll
    for (int r = 0; r < G1_ROWS; ++r) acc[r] = 0.f;
    #pragma unroll 4
    for (int k = 0; k < IN_DIM; ++k) {
        float wv = W1[k * HIDDEN + col];
        #pragma unroll
        for (int r = 0; r < G1_ROWS; ++r)
            acc[r] = fmaf(xs[r][k], wv, acc[r]);
    }
    #pragma unroll
    for (int r = 0; r < G1_ROWS; ++r)
        y[(long long)(row0 + r) * HIDDEN + col] = __float2bfloat16(acc[r]);
}

// ---- spmm1: h1 = relu(A @ y + b1); wave/node, bf16x2 per lane -------------
__global__ __launch_bounds__(256) void spmm1_kernel(const int* __restrict__ row_ptr,
                                                    const Edge* __restrict__ edges,
                                                    const __hip_bfloat16* __restrict__ y,
                                                    const float* __restrict__ b1,
                                                    __hip_bfloat16* __restrict__ h1)
{
    int node = blockIdx.x * 4 + (threadIdx.x >> 6);
    int lane = threadIdx.x & 63;
    if (node >= N_NODES) return;
    int beg = row_ptr[node];
    int end = row_ptr[node + 1];
    const __hip_bfloat162* yv = (const __hip_bfloat162*)y;
    float ax = 0.f, ay = 0.f;
    int j = beg;
    for (; j + 3 < end; j += 4) {
        Edge e0 = edges[j];
        Edge e1 = edges[j + 1];
        Edge e2 = edges[j + 2];
        Edge e3 = edges[j + 3];
        __hip_bfloat162 v0 = yv[(long long)e0.s * 64 + lane];
        __hip_bfloat162 v1 = yv[(long long)e1.s * 64 + lane];
        __hip_bfloat162 v2 = yv[(long long)e2.s * 64 + lane];
        __hip_bfloat162 v3 = yv[(long long)e3.s * 64 + lane];
        ax = fmaf(e0.w, __low2float(v0), ax);  ay = fmaf(e0.w, __high2float(v0), ay);
        ax = fmaf(e1.w, __low2float(v1), ax);  ay = fmaf(e1.w, __high2float(v1), ay);
        ax = fmaf(e2.w, __low2float(v2), ax);  ay = fmaf(e2.w, __high2float(v2), ay);
        ax = fmaf(e3.w, __low2float(v3), ax);  ay = fmaf(e3.w, __high2float(v3), ay);
    }
    for (; j < end; ++j) {
        Edge e0 = edges[j];
        __hip_bfloat162 v0 = yv[(long long)e0.s * 64 + lane];
        ax = fmaf(e0.w, __low2float(v0), ax);
        ay = fmaf(e0.w, __high2float(v0), ay);
    }
    float2 bv = ((const float2*)b1)[lane];
    float rx = fmaxf(ax + bv.x, 0.f);
    float ry = fmaxf(ay + bv.y, 0.f);
    __hip_bfloat162 hv;
    hv.x = __float2bfloat16(rx);
    hv.y = __float2bfloat16(ry);
    ((__hip_bfloat162*)h1)[(long long)node * 64 + lane] = hv;
}

// ---- gemm2: g = h1 @ W2 (bf16 in, bf16 out), 8 rows/block -----------------
#define G2_ROWS 8
__global__ __launch_bounds__(64) void gemm2_kernel(const __hip_bfloat16* __restrict__ h1,
                                                   const float* __restrict__ W2,
                                                   __hip_bfloat16* __restrict__ g)
{
    __shared__ float xs[G2_ROWS][HIDDEN];
    int row0 = blockIdx.x * G2_ROWS;
    int t = threadIdx.x;
    #pragma unroll
    for (int r = 0; r < G2_ROWS; ++r) {
        xs[r][t]      = __bfloat162float(h1[(long long)(row0 + r) * HIDDEN + t]);
        xs[r][t + 64] = __bfloat162float(h1[(long long)(row0 + r) * HIDDEN + t + 64]);
    }
    __syncthreads();
    if (t >= OUT_DIM) return;
    float acc[G2_ROWS];
    #pragma unroll
    for (int r = 0; r < G2_ROWS; ++r) acc[r] = 0.f;
    #pragma unroll 4
    for (int k = 0; k < HIDDEN; ++k) {
        float wv = W2[k * OUT_DIM + t];
        #pragma unroll
        for (int r = 0; r < G2_ROWS; ++r)
            acc[r] = fmaf(xs[r][k], wv, acc[r]);
    }
    #pragma unroll
    for (int r = 0; r < G2_ROWS; ++r)
        g[(long long)(row0 + r) * OUT_DIM + t] = __float2bfloat16(acc[r]);
}

// ---- spmm2: out = A @ g + b2; wave/node, 40 active lanes ------------------
__global__ __launch_bounds__(256) void spmm2_kernel(const int* __restrict__ row_ptr,
                                                    const Edge* __restrict__ edges,
                                                    const __hip_bfloat16* __restrict__ g,
                                                    const float* __restrict__ b2,
                                                    float* __restrict__ out)
{
    int node = blockIdx.x * 4 + (threadIdx.x >> 6);
    int lane = threadIdx.x & 63;
    if (node >= N_NODES) return;
    if (lane >= OUT_DIM) return;
    int beg = row_ptr[node];
    int end = row_ptr[node + 1];
    float acc = 0.f;
    int j = beg;
    for (; j + 3 < end; j += 4) {
        Edge e0 = edges[j];
        Edge e1 = edges[j + 1];
        Edge e2 = edges[j + 2];
        Edge e3 = edges[j + 3];
        float v0 = __bfloat162float(g[(long long)e0.s * OUT_DIM + lane]);
        float v1 = __bfloat162float(g[(long long)e1.s * OUT_DIM + lane]);
        float v2 = __bfloat162float(g[(long long)e2.s * OUT_DIM + lane]);
        float v3 = __bfloat162float(g[(long long)e3.s * OUT_DIM + lane]);
        acc = fmaf(e0.w, v0, acc);
        acc = fmaf(e1.w, v1, acc);
        acc = fmaf(e2.w, v2, acc);
        acc = fmaf(e3.w, v3, acc);
    }
    for (; j < end; ++j) {
        Edge e0 = edges[j];
        acc = fmaf(e0.w, __bfloat162float(g[(long long)e0.s * OUT_DIM + lane]), acc);
    }
    out[(long long)node * OUT_DIM + lane] = acc + b2[lane];
}

extern "C" void kernel_launch(void* const* d_in, const int* in_sizes, int n_in,
                              void* d_out, int out_size, void* d_ws, size_t ws_size,
                              hipStream_t stream)
{
    const float* x    = (const float*)d_in[0];
    const int*   esrc = (const int*)  d_in[1];
    const int*   edst = (const int*)  d_in[2];
    const float* ew   = (const float*)d_in[3];
    const float* W1   = (const float*)d_in[4];
    const float* b1   = (const float*)d_in[5];
    const float* W2   = (const float*)d_in[6];
    const float* b2   = (const float*)d_in[7];
    float* out = (float*)d_out;

    // workspace layout
    __hip_bfloat16* y  = (__hip_bfloat16*)d_ws;                  // 12.8 MB
    __hip_bfloat16* h1 = y  + (size_t)N_NODES * HIDDEN;          // 12.8 MB
    __hip_bfloat16* g  = h1 + (size_t)N_NODES * HIDDEN;          // 4.0 MB
    int* row_ptr    = (int*)(g + (size_t)N_NODES * OUT_DIM);     // 50001 (pad 50004)
    int* cursor     = row_ptr + 50004;
    int* block_sums = cursor + 50004;                            // 64 ints
    Edge* edges     = (Edge*)(block_sums + 64);                  // 6.4 MB

    const int nWaveBlocks = (N_NODES + 3) / 4;

    // build CSR (reused by both SpMMs)
    hipMemsetAsync(cursor, 0, N_NODES * sizeof(int), stream);
    hist_part<<<PART_BLOCKS, 256, 0, stream>>>(edst, cursor);
    scan_partial<<<SCAN_BLOCKS, SCAN_BS, 0, stream>>>(cursor, block_sums);
    scan_sums<<<1, 64, 0, stream>>>(block_sums, row_ptr);
    scan_final<<<SCAN_BLOCKS, SCAN_BS, 0, stream>>>(cursor, block_sums, row_ptr, cursor);
    scatter_part<<<PART_BLOCKS, 256, 0, stream>>>(esrc, edst, ew, cursor, edges);

    // y = x @ W1
    gemm1_kernel<<<N_NODES / G1_ROWS, 128, 0, stream>>>(x, W1, y);
    // h1 = relu(A @ y + b1)
    spmm1_kernel<<<nWaveBlocks, 256, 0, stream>>>(row_ptr, edges, y, b1, h1);
    // g = h1 @ W2
    gemm2_kernel<<<N_NODES / G2_ROWS, 64, 0, stream>>>(h1, W2, g);
    // out = A @ g + b2
    spmm2_kernel<<<nWaveBlocks, 256, 0, stream>>>(row_ptr, edges, g, b2, out);
}